// Round 11
// baseline (53.488 us; speedup 1.0000x reference)
//
#include <hip/hip_runtime.h>

// ContinuityLoss: loss = 0.01/(n(n-1)) * sum_{i!=j} exp(-|pi-pj|^2/2) * |oi-oj|
// points: [N,2] f32, outputs: [N,8] f32, scalar f32 out. N = 8192.
//
// R10: controlled experiment. R0's EXACT geometry (512 blocks = grid 8x64,
// BLK=256, MROW=4, TILE=128, LDS broadcast, 2 waves/SIMD) — the only
// structure measured at 80% VALUBusy — with ONLY the math swapped to fast
// (packed f32, exp2 w/ folded -0.5*log2(e), raw v_sqrt_f32) and two j-streams
// hoisted per iteration (8 independent dep-chains = 2 j x 4 rows).
// Full N^2 this round (one variable at a time; symmetry re-enters next).
// If this lands ~15-18us for cont_pairs: structure transfers, add symmetry.
// If ~25-30us: R0's slow math was the latency filler -> pipeline LDS next.

typedef float v2f __attribute__((ext_vector_type(2)));
typedef float v4f __attribute__((ext_vector_type(4)));

constexpr int BLK  = 256;            // threads per block (4 waves)
constexpr int MROW = 4;              // rows per thread
constexpr int TILE = 128;            // j-columns per block
constexpr int N    = 8192;
constexpr int ROWB = N / (BLK * MROW);   // 8 row blocks
constexpr int COLB = N / TILE;           // 64 col blocks (512 blocks total)

__global__ __launch_bounds__(BLK) void cont_pairs(
    const float* __restrict__ points, const float* __restrict__ outputs,
    double* __restrict__ partials)
{
    __shared__ v2f sp[TILE];
    __shared__ v4f soA[TILE];
    __shared__ v4f soB[TILE];

    const int tid = threadIdx.x;
    const int rb  = blockIdx.x;
    const int cb  = blockIdx.y;
    const int jbase = cb * TILE;

    if (tid < TILE) {
        const int j = jbase + tid;
        sp[tid]  = reinterpret_cast<const v2f*>(points)[j];
        const v4f* o = reinterpret_cast<const v4f*>(outputs + 8 * j);
        soA[tid] = o[0];
        soB[tid] = o[1];
    }

    // i-side: MROW rows per thread (coalesced: rows BLK apart)
    v2f pi[MROW];
    v4f oiA[MROW], oiB[MROW];
    const int ibase = rb * BLK * MROW + tid;
    #pragma unroll
    for (int k = 0; k < MROW; ++k) {
        const int i = ibase + k * BLK;
        pi[k] = reinterpret_cast<const v2f*>(points)[i];
        const v4f* o = reinterpret_cast<const v4f*>(outputs + 8 * i);
        oiA[k] = o[0];
        oiB[k] = o[1];
    }
    __syncthreads();

    constexpr float kE = -0.72134752044f;   // -0.5 * log2(e)
    float accA[MROW] = {0.f, 0.f, 0.f, 0.f};
    float accB[MROW] = {0.f, 0.f, 0.f, 0.f};

    #pragma unroll 2
    for (int jj = 0; jj < TILE; jj += 2) {
        // two j-streams hoisted -> 8 independent chains (2 j x 4 rows)
        const v2f pj0 = sp[jj];     const v2f pj1 = sp[jj + 1];
        const v4f a0  = soA[jj];    const v4f a1  = soA[jj + 1];
        const v4f c0  = soB[jj];    const v4f c1  = soB[jj + 1];
        #pragma unroll
        for (int k = 0; k < MROW; ++k) {
            {   v2f dp = pi[k] - pj0;
                float d2 = dp.x * dp.x + dp.y * dp.y;
                float w  = __builtin_amdgcn_exp2f(d2 * kE);
                v4f t0 = oiA[k] - a0;
                v4f t1 = oiB[k] - c0;
                v4f q  = t0 * t0;
                q += t1 * t1;
                float dd = (q.x + q.y) + (q.z + q.w);
                accA[k] += w * __builtin_amdgcn_sqrtf(dd);  // i==j adds 0
            }
            {   v2f dp = pi[k] - pj1;
                float d2 = dp.x * dp.x + dp.y * dp.y;
                float w  = __builtin_amdgcn_exp2f(d2 * kE);
                v4f t0 = oiA[k] - a1;
                v4f t1 = oiB[k] - c1;
                v4f q  = t0 * t0;
                q += t1 * t1;
                float dd = (q.x + q.y) + (q.z + q.w);
                accB[k] += w * __builtin_amdgcn_sqrtf(dd);
            }
        }
    }

    float sum = ((accA[0] + accA[1]) + (accA[2] + accA[3]))
              + ((accB[0] + accB[1]) + (accB[2] + accB[3]));
    #pragma unroll
    for (int off = 32; off > 0; off >>= 1)
        sum += __shfl_down(sum, off, 64);

    __shared__ float wpart[BLK / 64];
    if ((tid & 63) == 0) wpart[tid >> 6] = sum;
    __syncthreads();
    if (tid == 0) {
        double d = 0.0;
        #pragma unroll
        for (int w = 0; w < BLK / 64; ++w) d += (double)wpart[w];
        partials[(size_t)cb * ROWB + rb] = d;
    }
}

__global__ __launch_bounds__(256) void cont_final(
    const double* __restrict__ partials, int nparts,
    float* __restrict__ out, double scale)
{
    const int tid = threadIdx.x;
    double sum = 0.0;
    for (int i = tid; i < nparts; i += 256) sum += partials[i];
    #pragma unroll
    for (int off = 32; off > 0; off >>= 1)
        sum += __shfl_down(sum, off, 64);

    __shared__ double ws[256 / 64];
    if ((tid & 63) == 0) ws[tid >> 6] = sum;
    __syncthreads();
    if (tid == 0) {
        double t = 0.0;
        #pragma unroll
        for (int w = 0; w < 256 / 64; ++w) t += ws[w];
        out[0] = (float)(t * scale);
    }
}

extern "C" void kernel_launch(void* const* d_in, const int* in_sizes, int n_in,
                              void* d_out, int out_size, void* d_ws, size_t ws_size,
                              hipStream_t stream) {
    const float* points  = (const float*)d_in[0];
    const float* outputs = (const float*)d_in[1];
    float* out = (float*)d_out;

    const int n = in_sizes[0] / 2;             // 8192
    const int nparts = ROWB * COLB;            // 512
    double* partials = (double*)d_ws;          // 4 KB scratch

    cont_pairs<<<dim3(ROWB, COLB), dim3(BLK), 0, stream>>>(points, outputs, partials);

    const double scale = 0.01 / ((double)n * (double)(n - 1));
    cont_final<<<1, 256, 0, stream>>>(partials, nparts, out, scale);
}

// Round 12
// 30.976 us; speedup vs baseline: 1.7268x; 1.7268x over previous
//
#include <hip/hip_runtime.h>
#include <hip/hip_bf16.h>

// ContinuityLoss: loss = 0.01/(n(n-1)) * sum_{i!=j} exp(-|pi-pj|^2/2) * |oi-oj|
// points: [N,2] f32, outputs: [N,8] f32, scalar f32 out. N = 8192.
//
// R11: MFMA rewrite. Both pairwise-distance dot products are GEMMs:
//   |oi-oj|^2 = on_i + on_j - 2*(O O^T)_ij   (K=8,  bf16 mfma, zero-padded)
//   |pi-pj|^2 = pn_i + pn_j - 2*(P P^T)_ij   (K=2,  bf16 mfma, zero-padded)
// Norms in exact f32 (precomputed per block into LDS). Per pair only the
// irreducible elementwise remains: ~7 VALU + exp2 + sqrt (~30 cyc/64 pairs
// vs 130 measured for the pure-VALU R10). bf16 input rounding contributes
// <= ~4e-6 correlated error on the loss (threshold 7.4e-5).
// Fragment layouts (m89/m91-verified): A/B lane l: row/col=l&15, k=(l>>4)*8+e
// (k>=8 zeroed); C/D: col=l&15, row=(l>>4)*4+reg. Diagonal killed by (j>i)
// select (also suppresses bf16 cancellation noise at i==j).
// Work split: upper-tri at (64-row panel) x (256-col chunk) granularity ->
// exactly 2112 one-wave blocks (8.25 waves/CU); (j>i) predicate only in the
// 128 straddling blocks; all kept pairs weighted 2 via the global scale.

typedef float v2f __attribute__((ext_vector_type(2)));
typedef float v4f __attribute__((ext_vector_type(4)));
typedef short bf16x8 __attribute__((ext_vector_type(8)));
typedef float f32x4 __attribute__((ext_vector_type(4)));

constexpr int N    = 8192;
constexpr int PROW = 64;          // rows per block (1 wave)
constexpr int CCOL = 256;         // cols per block
constexpr int NIT  = PROW / 16;   // 4 i-tiles
constexpr int NJT  = CCOL / 16;   // 16 j-tiles
constexpr int NCH  = N / CCOL;    // 32 col chunks
constexpr int NBLOCKS = 2112;     // sum_{m=0}^{31} 4*(32-m) = 4*528

constexpr float KE   = -0.72134752044448169f;  // -0.5*log2(e)
constexpr float M2KE =  1.4426950408889634f;   // -2*KE = log2(e)

struct TrueT  { static constexpr bool value = true;  };
struct FalseT { static constexpr bool value = false; };

__device__ __forceinline__ short f2bf(float f) {
    __hip_bfloat16 h = __float2bfloat16(f);
    return __builtin_bit_cast(short, h);
}

__device__ __forceinline__ float dot8(const float* __restrict__ row) {
    const v4f* o = reinterpret_cast<const v4f*>(row);
    v4f a = o[0], b = o[1];
    v4f q = a * a + b * b;
    return (q.x + q.y) + (q.z + q.w);
}

__global__ __launch_bounds__(64) void cont_pairs(
    const float* __restrict__ points, const float* __restrict__ outputs,
    double* __restrict__ partials)
{
    // decode block -> (panel p of 64 rows, chunk c of 256 cols), upper-tri:
    // group m = floor(p/4): panels 4m..4m+3, chunks c = m..31
    const int b = blockIdx.x;
    int m = 0, base = 0;
    while (b >= base + 4 * (NCH - m)) { base += 4 * (NCH - m); ++m; }
    const int off = b - base;
    const int len = NCH - m;
    const int p = 4 * m + off / len;
    const int c = m + off % len;
    const bool diag = (c == m);          // block straddles the diagonal

    const int rowbase = p * PROW;
    const int colbase = c * CCOL;

    const int lane = threadIdx.x;        // 0..63
    const int q  = lane >> 4;            // quad 0..3
    const int cl = lane & 15;

    __shared__ float s_onj[CCOL], s_pnj[CCOL];
    __shared__ float s_oni[PROW], s_pni[PROW];

    // prologue: exact f32 norms for this block's rows and cols
    {
        const int i = rowbase + lane;
        s_oni[lane] = dot8(outputs + 8 * i);
        v2f pp = reinterpret_cast<const v2f*>(points)[i];
        s_pni[lane] = KE * (pp.x * pp.x + pp.y * pp.y);
        #pragma unroll
        for (int t = 0; t < 4; ++t) {
            const int j = colbase + t * 64 + lane;
            s_onj[t * 64 + lane] = dot8(outputs + 8 * j);
            v2f pq = reinterpret_cast<const v2f*>(points)[j];
            s_pnj[t * 64 + lane] = KE * (pq.x * pq.x + pq.y * pq.y);
        }
    }
    __syncthreads();

    // i-side fragments + row norms in registers
    bf16x8 aO[NIT], aP[NIT];
    float onR[NIT][4], pnR[NIT][4];
    const bf16x8 z8 = {0, 0, 0, 0, 0, 0, 0, 0};
    #pragma unroll
    for (int it = 0; it < NIT; ++it) {
        const int i = rowbase + it * 16 + cl;
        const v4f* o = reinterpret_cast<const v4f*>(outputs + 8 * i);
        v4f x = o[0], y = o[1];
        bf16x8 v = {f2bf(x.x), f2bf(x.y), f2bf(x.z), f2bf(x.w),
                    f2bf(y.x), f2bf(y.y), f2bf(y.z), f2bf(y.w)};
        v2f pp = reinterpret_cast<const v2f*>(points)[i];
        bf16x8 vp = {f2bf(pp.x), f2bf(pp.y), 0, 0, 0, 0, 0, 0};
        aO[it] = (q == 0) ? v  : z8;     // k = q*8+e; only k<8 valid
        aP[it] = (q == 0) ? vp : z8;
        #pragma unroll
        for (int e = 0; e < 4; ++e) {
            onR[it][e] = s_oni[it * 16 + q * 4 + e];
            pnR[it][e] = s_pni[it * 16 + q * 4 + e];
        }
    }

    float accS = 0.f;

    auto body = [&](auto DG) {
        #pragma unroll 2
        for (int jt = 0; jt < NJT; ++jt) {
            const int jrow = colbase + jt * 16 + cl;
            const v4f* oj = reinterpret_cast<const v4f*>(outputs + 8 * jrow);
            v4f x = oj[0], y = oj[1];
            bf16x8 bO = {f2bf(x.x), f2bf(x.y), f2bf(x.z), f2bf(x.w),
                         f2bf(y.x), f2bf(y.y), f2bf(y.z), f2bf(y.w)};
            v2f pj = reinterpret_cast<const v2f*>(points)[jrow];
            bf16x8 bP = {f2bf(pj.x), f2bf(pj.y), 0, 0, 0, 0, 0, 0};
            if (q != 0) { bO = z8; bP = z8; }
            const float onC = s_onj[jt * 16 + cl];
            const float pnC = s_pnj[jt * 16 + cl];
            #pragma unroll
            for (int it = 0; it < NIT; ++it) {
                const f32x4 z = {0.f, 0.f, 0.f, 0.f};
                f32x4 dO = __builtin_amdgcn_mfma_f32_16x16x32_bf16(aO[it], bO, z, 0, 0, 0);
                f32x4 dP = __builtin_amdgcn_mfma_f32_16x16x32_bf16(aP[it], bP, z, 0, 0, 0);
                #pragma unroll
                for (int e = 0; e < 4; ++e) {
                    float dd = fmaf(-2.f, dO[e], onR[it][e] + onC);
                    dd = fmaxf(dd, 0.f);
                    float diff = __builtin_amdgcn_sqrtf(dd);
                    float w = __builtin_amdgcn_exp2f(
                        fmaf(M2KE, dP[e], pnR[it][e] + pnC));
                    if constexpr (decltype(DG)::value) {
                        const int rg = rowbase + it * 16 + q * 4 + e;
                        diff = (jrow > rg) ? diff : 0.f;
                    }
                    accS = fmaf(w, diff, accS);
                }
            }
        }
    };
    if (diag) body(TrueT{}); else body(FalseT{});

    #pragma unroll
    for (int o = 32; o > 0; o >>= 1)
        accS += __shfl_down(accS, o, 64);
    if (lane == 0) partials[b] = (double)accS;
}

__global__ __launch_bounds__(1024) void cont_final(
    const double* __restrict__ partials, int nparts,
    float* __restrict__ out, double scale)
{
    const int tid = threadIdx.x;
    double sum = 0.0;
    for (int i = tid; i < nparts; i += 1024) sum += partials[i];
    #pragma unroll
    for (int off = 32; off > 0; off >>= 1)
        sum += __shfl_down(sum, off, 64);

    __shared__ double ws[1024 / 64];
    if ((tid & 63) == 0) ws[tid >> 6] = sum;
    __syncthreads();
    if (tid == 0) {
        double t = 0.0;
        #pragma unroll
        for (int w = 0; w < 1024 / 64; ++w) t += ws[w];
        out[0] = (float)(t * scale);
    }
}

extern "C" void kernel_launch(void* const* d_in, const int* in_sizes, int n_in,
                              void* d_out, int out_size, void* d_ws, size_t ws_size,
                              hipStream_t stream) {
    const float* points  = (const float*)d_in[0];
    const float* outputs = (const float*)d_in[1];
    float* out = (float*)d_out;

    const int n = in_sizes[0] / 2;             // 8192
    double* partials = (double*)d_ws;          // 2112 * 8B = 16.9 KB scratch

    cont_pairs<<<dim3(NBLOCKS), dim3(64), 0, stream>>>(points, outputs, partials);

    // each unordered pair counted once -> weight 2 folded into the scale
    const double scale = 0.01 * 2.0 / ((double)n * (double)(n - 1));
    cont_final<<<1, 1024, 0, stream>>>(partials, NBLOCKS, out, scale);
}

// Round 13
// 27.666 us; speedup vs baseline: 1.9334x; 1.1197x over previous
//
#include <hip/hip_runtime.h>

// ContinuityLoss: loss = 0.01/(n(n-1)) * sum_{i!=j} exp(-|pi-pj|^2/2) * |oi-oj|
// points: [N,2] f32, outputs: [N,8] f32, scalar f32 out. N = 8192.
//
// R12: norm-augmented MFMA. Fold the distance expansion INTO the matmul's K:
//   A_O = [o_i(8), |o_i|^2, 1]       B_O = [-2*o_j(8), 1, |o_j|^2]   (K=10)
//     -> one mfma emits dd_ij = |oi-oj|^2 complete.
//   A_P = [p_i(2), KE*pn_i, 1]       B_P = [M2*p_j(2), 1, KE*pn_j]   (K=4)
//     -> one mfma emits the finished exp2 argument  (KE=-log2(e)/2, M2=-2KE).
// Epilogue per pair: fmax, sqrt, exp2, fma  (4 ops vs R10's ~26).
// mfma_f32_16x16x16_f16: 2-VGPR operands; f16 (10-bit mantissa) beats R11's
// bf16. A/B layout: row/col=l&15, k=(l>>4)*4+e (analog of m89-verified x32);
// a C/D row<->col error cancels in a scalar total, so layout risk is low.
// One 64x64 pair-tile per wave; triangular 128x128 tile grid -> 8256 1-wave
// blocks (~8 waves/SIMD, 4x R11's TLP). No LDS; state ~16 VGPR of fragments.
// Diagonal tiles (128 of 8256) mask j>i per element; scale carries the x2.

typedef float v2f __attribute__((ext_vector_type(2)));
typedef float v4f __attribute__((ext_vector_type(4)));
typedef _Float16 h4 __attribute__((ext_vector_type(4)));
typedef float f32x4 __attribute__((ext_vector_type(4)));

constexpr int N_PTS = 8192;
constexpr int TDIM  = N_PTS / 64;               // 128 tiles per side
constexpr int NBLOCKS = TDIM * (TDIM + 1) / 2;  // 8256

constexpr float KE = -0.72134752044448169f;  // -0.5*log2(e)
constexpr float M2 =  1.4426950408889634f;   // -2*KE = log2(e)

__device__ __forceinline__ int tri_before(int r) {
    return r * TDIM - (r * (r - 1)) / 2;     // blocks before tile-row r
}

__global__ __launch_bounds__(64, 6) void cont_pairs(
    const float* __restrict__ points, const float* __restrict__ outputs,
    double* __restrict__ partials)
{
    const int b = blockIdx.x;
    // closed-form upper-tri decode + exact integer fixup
    int ti = (int)((2 * TDIM + 1 -
                    sqrtf((float)((2 * TDIM + 1) * (2 * TDIM + 1) - 8 * b))) * 0.5f);
    ti = ti < 0 ? 0 : (ti > TDIM - 1 ? TDIM - 1 : ti);
    while (tri_before(ti + 1) <= b) ++ti;
    while (tri_before(ti) > b) --ti;
    const int tj = ti + (b - tri_before(ti));
    const bool diag = (ti == tj);

    const int lane = threadIdx.x;            // 0..63
    const int q = lane >> 4, cl = lane & 15;
    const int rowbase = ti * 64, colbase = tj * 64;

    const _Float16 h0 = (_Float16)0.f, h1 = (_Float16)1.f;

    // i-side fragments (A operands), norm-augmented
    h4 aO[4], aP[4];
    #pragma unroll
    for (int it = 0; it < 4; ++it) {
        const int i = rowbase + it * 16 + cl;
        const v4f* o = reinterpret_cast<const v4f*>(outputs + 8 * i);
        const v4f x = o[0], y = o[1];
        const v4f s = x * x + y * y;
        const float on = (s.x + s.y) + (s.z + s.w);
        const v2f p = reinterpret_cast<const v2f*>(points)[i];
        const float pn = p.x * p.x + p.y * p.y;
        h4 a;
        if (q == 0)      a = h4{(_Float16)x.x, (_Float16)x.y, (_Float16)x.z, (_Float16)x.w};
        else if (q == 1) a = h4{(_Float16)y.x, (_Float16)y.y, (_Float16)y.z, (_Float16)y.w};
        else if (q == 2) a = h4{(_Float16)on, h1, h0, h0};
        else             a = h4{h0, h0, h0, h0};
        aO[it] = a;
        if (q == 0) aP[it] = h4{(_Float16)p.x, (_Float16)p.y, (_Float16)(KE * pn), h1};
        else        aP[it] = h4{h0, h0, h0, h0};
    }

    float accS = 0.f;

    #pragma unroll 2
    for (int jt = 0; jt < 4; ++jt) {
        // j-side fragments (B operands), norm-augmented, -2 folded in
        const int j = colbase + jt * 16 + cl;
        const v4f* o = reinterpret_cast<const v4f*>(outputs + 8 * j);
        const v4f x = o[0], y = o[1];
        const v4f s = x * x + y * y;
        const float on = (s.x + s.y) + (s.z + s.w);
        const v2f p = reinterpret_cast<const v2f*>(points)[j];
        const float pn = p.x * p.x + p.y * p.y;
        h4 bO, bP;
        if (q == 0)      bO = h4{(_Float16)(-2.f * x.x), (_Float16)(-2.f * x.y),
                                 (_Float16)(-2.f * x.z), (_Float16)(-2.f * x.w)};
        else if (q == 1) bO = h4{(_Float16)(-2.f * y.x), (_Float16)(-2.f * y.y),
                                 (_Float16)(-2.f * y.z), (_Float16)(-2.f * y.w)};
        else if (q == 2) bO = h4{h1, (_Float16)on, h0, h0};
        else             bO = h4{h0, h0, h0, h0};
        if (q == 0) bP = h4{(_Float16)(M2 * p.x), (_Float16)(M2 * p.y), h1,
                            (_Float16)(KE * pn)};
        else        bP = h4{h0, h0, h0, h0};

        #pragma unroll
        for (int it = 0; it < 4; ++it) {
            const f32x4 z = {0.f, 0.f, 0.f, 0.f};
            f32x4 dO = __builtin_amdgcn_mfma_f32_16x16x16f16(aO[it], bO, z, 0, 0, 0);
            f32x4 dP = __builtin_amdgcn_mfma_f32_16x16x16f16(aP[it], bP, z, 0, 0, 0);
            #pragma unroll
            for (int e = 0; e < 4; ++e) {
                float diff = __builtin_amdgcn_sqrtf(fmaxf(dO[e], 0.f));
                if (diag) {
                    const int irow = it * 16 + q * 4 + e;   // C/D row
                    const int jcol = jt * 16 + cl;          // C/D col
                    diff = (jcol > irow) ? diff : 0.f;
                }
                accS = fmaf(__builtin_amdgcn_exp2f(dP[e]), diff, accS);
            }
        }
    }

    #pragma unroll
    for (int off = 32; off > 0; off >>= 1)
        accS += __shfl_down(accS, off, 64);
    if (lane == 0) partials[b] = (double)accS;
}

__global__ __launch_bounds__(1024) void cont_final(
    const double* __restrict__ partials, int nparts,
    float* __restrict__ out, double scale)
{
    const int tid = threadIdx.x;
    double sum = 0.0;
    for (int i = tid; i < nparts; i += 1024) sum += partials[i];
    #pragma unroll
    for (int off = 32; off > 0; off >>= 1)
        sum += __shfl_down(sum, off, 64);

    __shared__ double ws[1024 / 64];
    if ((tid & 63) == 0) ws[tid >> 6] = sum;
    __syncthreads();
    if (tid == 0) {
        double t = 0.0;
        #pragma unroll
        for (int w = 0; w < 1024 / 64; ++w) t += ws[w];
        out[0] = (float)(t * scale);
    }
}

extern "C" void kernel_launch(void* const* d_in, const int* in_sizes, int n_in,
                              void* d_out, int out_size, void* d_ws, size_t ws_size,
                              hipStream_t stream) {
    const float* points  = (const float*)d_in[0];
    const float* outputs = (const float*)d_in[1];
    float* out = (float*)d_out;

    const int n = in_sizes[0] / 2;             // 8192
    double* partials = (double*)d_ws;          // 8256 * 8B = 66 KB scratch

    cont_pairs<<<dim3(NBLOCKS), dim3(64), 0, stream>>>(points, outputs, partials);

    // each unordered pair counted once -> weight 2 folded into the scale
    const double scale = 0.01 * 2.0 / ((double)n * (double)(n - 1));
    cont_final<<<1, 1024, 0, stream>>>(partials, NBLOCKS, out, scale);
}